// Round 1
// baseline (482.183 us; speedup 1.0000x reference)
//
#include <hip/hip_runtime.h>
#include <hip/hip_bf16.h>

// Attention_aux: fused aux-attention scorer + context + output projection.
// Pipeline:
//   1. convw1:   W1[:, :3072] -> bf16 (ws)                       [6.3 MB]
//   2. hbias:    hb[b,d] = hs[b,:]·W1[d,3072:] + b1[d]  (fp32)
//   3. gemm_score: bf16 MFMA  pre = enc·W1a^T ; fused epilogue
//                  p = sum_d tanh(pre+hb)*w2[d] -> pe[row][16]   (deterministic)
//   4. softmax over S -> alpha
//   5. ctxpart/ctxreduce: context = alpha^T · enc  (fp32, 2-stage, deterministic)
//   6. final:    out = context·W3^T + b3  (fp32, wave-per-(b,d))

typedef float          fx4 __attribute__((ext_vector_type(4)));
typedef short          sv8 __attribute__((ext_vector_type(8)));
typedef unsigned short uv8 __attribute__((ext_vector_type(8)));
typedef unsigned short uv4 __attribute__((ext_vector_type(4)));

// RNE float -> bf16 (inputs are finite; no NaN path needed)
__device__ __forceinline__ unsigned short f2bf(float x) {
  unsigned u = __float_as_uint(x);
  return (unsigned short)((u + 0x7FFFu + ((u >> 16) & 1u)) >> 16);
}

__device__ __forceinline__ uv8 pack8(fx4 a, fx4 b) {
  uv8 v;
  v[0] = f2bf(a[0]); v[1] = f2bf(a[1]); v[2] = f2bf(a[2]); v[3] = f2bf(a[3]);
  v[4] = f2bf(b[0]); v[5] = f2bf(b[1]); v[6] = f2bf(b[2]); v[7] = f2bf(b[3]);
  return v;
}

// ---------------- kernel 1: convert W1[:, :3072] to bf16 ----------------
__global__ void convw1_kernel(const float* __restrict__ W1, unsigned short* __restrict__ W1a) {
  int id = blockIdx.x * 256 + threadIdx.x;      // float4 id, 1024*768 total
  int d = id / 768, fi = id - d * 768;
  fx4 v = ((const fx4*)W1)[d * 1024 + fi];      // W1 row = 4096 floats = 1024 fx4
  uv4 r; r[0] = f2bf(v[0]); r[1] = f2bf(v[1]); r[2] = f2bf(v[2]); r[3] = f2bf(v[3]);
  ((uv4*)W1a)[d * 768 + fi] = r;
}

// ---------------- kernel 2: hidden-state bias  hb[b,d] ----------------
__global__ void hbias_kernel(const float* __restrict__ hs, const float* __restrict__ W1,
                             const float* __restrict__ b1, float* __restrict__ hb) {
  int idx = (blockIdx.x << 2) + (threadIdx.x >> 6);   // 0..32767 = b*1024+d
  int lane = threadIdx.x & 63;
  int b = idx >> 10, d = idx & 1023;
  const fx4* hv = (const fx4*)hs;
  const fx4* wv = (const fx4*)W1;
  float s = 0.f;
#pragma unroll
  for (int i = 0; i < 4; ++i) {
    int k4 = lane + (i << 6);
    fx4 h = hv[(b << 8) + k4];
    fx4 w = wv[d * 1024 + 768 + k4];          // last 1024 cols of W1 row d
    s += h[0] * w[0] + h[1] * w[1] + h[2] * w[2] + h[3] * w[3];
  }
#pragma unroll
  for (int off = 32; off; off >>= 1) s += __shfl_xor(s, off);
  if (lane == 0) hb[idx] = s + b1[d];
}

// ---------------- kernel 3: big GEMM + tanh·w2 epilogue ----------------
// M=32768, N=1024, K=3072. A = enc fp32 (reg-staged -> bf16), B = W1a bf16.
// 128x128 tile, BK=32, 4 waves (2x2), 16x16x32 MFMA, swizzled LDS.
__global__ __launch_bounds__(256, 2)
void gemm_score(const float* __restrict__ enc,
                const unsigned short* __restrict__ W1a,
                const float* __restrict__ hb,
                const float* __restrict__ w2,
                float* __restrict__ pe) {
  __shared__ __align__(16) unsigned short As[4096];   // 128 rows x 32 k (bf16)
  __shared__ __align__(16) unsigned short Bs[4096];

  const int t = threadIdx.x;
  const int lane = t & 63, wid = t >> 6;
  const int wm = wid >> 1, wn = wid & 1;

  // XCD-bijective swizzle: 2048 blocks, XCD x owns contiguous logical [x*256, +256)
  const int bid = blockIdx.x;
  const int lg = ((bid & 7) << 8) | (bid >> 3);
  const int mt = lg >> 3, nt = lg & 7;
  const int row0 = mt << 7;
  const int col0 = nt << 7;

  const fx4* encv = (const fx4*)enc;     // row stride 768 fx4
  const uv8* w1v = (const uv8*)W1a;      // row stride 384 uv8

  fx4 acc[4][4] = {};

  // staging: 512 chunks of 16B per tile; thread t owns chunks t and t+256
  const int c0 = t, c1 = t + 256;
  const int ar0 = c0 >> 2, as0 = c0 & 3;
  const int ar1 = c1 >> 2, as1 = c1 & 3;
  // swizzled LDS element offsets (slot ^= (row>>1)&3, 8-elem slots)
  const int st0 = ar0 * 32 + (((as0 ^ (ar0 >> 1)) & 3) << 3);
  const int st1 = ar1 * 32 + (((as1 ^ (ar1 >> 1)) & 3) << 3);
  const int ag0 = (row0 + ar0) * 768 + as0 * 2;
  const int ag1 = (row0 + ar1) * 768 + as1 * 2;
  const int bg0 = (col0 + ar0) * 384 + as0;
  const int bg1 = (col0 + ar1) * 384 + as1;

  fx4 pa0, pa1, pa2, pa3;
  uv8 pb0, pb1;

  // fragment read offsets (same swizzle)
  const int r15 = lane & 15, q = lane >> 4;
  const int sel = (q ^ (r15 >> 1)) & 3;
  const int offA = (wm * 64 + r15) * 32 + (sel << 3);
  const int offB = (wn * 64 + r15) * 32 + (sel << 3);

  // prologue: load + store tile 0
  pa0 = encv[ag0]; pa1 = encv[ag0 + 1];
  pa2 = encv[ag1]; pa3 = encv[ag1 + 1];
  pb0 = w1v[bg0];  pb1 = w1v[bg1];
  *(uv8*)&As[st0] = pack8(pa0, pa1);
  *(uv8*)&As[st1] = pack8(pa2, pa3);
  *(uv8*)&Bs[st0] = pb0;
  *(uv8*)&Bs[st1] = pb1;
  __syncthreads();

  for (int kt = 0; kt < 96; ++kt) {
    if (kt < 95) {                       // prefetch next tile into regs
      const int k8 = (kt + 1) * 8, k4 = (kt + 1) * 4;
      pa0 = encv[ag0 + k8]; pa1 = encv[ag0 + k8 + 1];
      pa2 = encv[ag1 + k8]; pa3 = encv[ag1 + k8 + 1];
      pb0 = w1v[bg0 + k4];  pb1 = w1v[bg1 + k4];
    }
    sv8 af[4], bf[4];
#pragma unroll
    for (int mi = 0; mi < 4; ++mi) af[mi] = *(const sv8*)&As[offA + mi * 512];
#pragma unroll
    for (int ni = 0; ni < 4; ++ni) bf[ni] = *(const sv8*)&Bs[offB + ni * 512];
#pragma unroll
    for (int mi = 0; mi < 4; ++mi)
#pragma unroll
      for (int ni = 0; ni < 4; ++ni)
        acc[mi][ni] = __builtin_amdgcn_mfma_f32_16x16x32_bf16(af[mi], bf[ni], acc[mi][ni], 0, 0, 0);
    __syncthreads();                     // everyone done reading LDS
    if (kt < 95) {
      *(uv8*)&As[st0] = pack8(pa0, pa1);
      *(uv8*)&As[st1] = pack8(pa2, pa3);
      *(uv8*)&Bs[st0] = pb0;
      *(uv8*)&Bs[st1] = pb1;
    }
    __syncthreads();                     // next tile visible
  }

  // epilogue: p[row] += sum_{cols in this tile} tanh(acc + hb) * w2
  // C/D layout (m89): col = lane&15, row = (lane>>4)*4 + j
  const int b = row0 >> 10;
  float w2v[4], hbv[4];
#pragma unroll
  for (int ni = 0; ni < 4; ++ni) {
    int c = col0 + wn * 64 + ni * 16 + r15;
    w2v[ni] = w2[c];
    hbv[ni] = hb[(b << 10) + c];
  }
#pragma unroll
  for (int mi = 0; mi < 4; ++mi) {
#pragma unroll
    for (int j = 0; j < 4; ++j) {
      float p = 0.f;
#pragma unroll
      for (int ni = 0; ni < 4; ++ni)
        p += tanhf(acc[mi][ni][j] + hbv[ni]) * w2v[ni];
      p += __shfl_xor(p, 1); p += __shfl_xor(p, 2);
      p += __shfl_xor(p, 4); p += __shfl_xor(p, 8);
      if (r15 == 0) {
        int row = row0 + wm * 64 + mi * 16 + (q << 2) + j;
        pe[(row << 4) + (nt << 1) + wn] = p;   // 16 deterministic slots per row
      }
    }
  }
}

// ---------------- kernel 4: softmax over S per batch ----------------
__global__ void softmax_kernel(const float* __restrict__ pe, float* __restrict__ alpha) {
  int b = blockIdx.x, t = threadIdx.x;
  int lane = t & 63, wid = t >> 6;
  float ev[4];
#pragma unroll
  for (int r = 0; r < 4; ++r) {
    int s = t + r * 256;
    const float* p = pe + ((b << 10) + s) * 16;
    float sum = 0.f;
#pragma unroll
    for (int i = 0; i < 16; ++i) sum += p[i];
    ev[r] = sum;
  }
  float m = fmaxf(fmaxf(ev[0], ev[1]), fmaxf(ev[2], ev[3]));
#pragma unroll
  for (int off = 32; off; off >>= 1) m = fmaxf(m, __shfl_xor(m, off));
  __shared__ float red[8];
  if (lane == 0) red[wid] = m;
  __syncthreads();
  m = fmaxf(fmaxf(red[0], red[1]), fmaxf(red[2], red[3]));
  float p4[4], ls = 0.f;
#pragma unroll
  for (int r = 0; r < 4; ++r) { p4[r] = expf(ev[r] - m); ls += p4[r]; }
#pragma unroll
  for (int off = 32; off; off >>= 1) ls += __shfl_xor(ls, off);
  if (lane == 0) red[4 + wid] = ls;
  __syncthreads();
  float inv = 1.0f / (red[4] + red[5] + red[6] + red[7]);
#pragma unroll
  for (int r = 0; r < 4; ++r) alpha[(b << 10) + t + r * 256] = p4[r] * inv;
}

// ---------------- kernel 5: context partials over s-chunks ----------------
__global__ void ctxpart_kernel(const float* __restrict__ enc, const float* __restrict__ alpha,
                               float* __restrict__ part) {
  int bid = blockIdx.x, b = bid >> 4, sc = bid & 15;
  int t = threadIdx.x;
  __shared__ float sal[64];
  if (t < 64) sal[t] = alpha[(b << 10) + (sc << 6) + t];
  __syncthreads();
  const fx4* ev = (const fx4*)enc;
  fx4 a0 = {}, a1 = {}, a2 = {};
  int base = ((b << 10) + (sc << 6)) * 768;
  for (int si = 0; si < 64; ++si) {
    float a = sal[si];
    const fx4* rp = ev + base + si * 768;
    a0 += a * rp[t];
    a1 += a * rp[256 + t];
    a2 += a * rp[512 + t];
  }
  fx4* pp = (fx4*)part;
  int pb = ((b << 4) + sc) * 768;
  pp[pb + t] = a0; pp[pb + 256 + t] = a1; pp[pb + 512 + t] = a2;
}

__global__ void ctxreduce_kernel(const float* __restrict__ part, float* __restrict__ ctx) {
  int j = blockIdx.x * 256 + threadIdx.x;     // 0..24575 fx4
  int b = j / 768, fi = j - b * 768;
  const fx4* pp = (const fx4*)part;
  fx4 s = {};
#pragma unroll
  for (int i = 0; i < 16; ++i) s += pp[((b << 4) + i) * 768 + fi];
  ((fx4*)ctx)[b * 768 + fi] = s;
}

// ---------------- kernel 6: out = ctx·W3^T + b3 ----------------
__global__ void final_kernel(const float* __restrict__ ctx, const float* __restrict__ W3,
                             const float* __restrict__ b3, float* __restrict__ out) {
  int idx = (blockIdx.x << 2) + (threadIdx.x >> 6);   // b*1024 + d
  int lane = threadIdx.x & 63;
  int b = idx >> 10, d = idx & 1023;
  const fx4* cv = (const fx4*)ctx;
  const fx4* wv = (const fx4*)W3;
  float s = 0.f;
#pragma unroll
  for (int i = 0; i < 12; ++i) {
    int f4 = lane + (i << 6);
    fx4 c = cv[b * 768 + f4];
    fx4 w = wv[d * 768 + f4];
    s += c[0] * w[0] + c[1] * w[1] + c[2] * w[2] + c[3] * w[3];
  }
#pragma unroll
  for (int off = 32; off; off >>= 1) s += __shfl_xor(s, off);
  if (lane == 0) out[idx] = s + b3[d];
}

extern "C" void kernel_launch(void* const* d_in, const int* in_sizes, int n_in,
                              void* d_out, int out_size, void* d_ws, size_t ws_size,
                              hipStream_t stream) {
  const float* hs  = (const float*)d_in[0];   // (32, 1024)
  const float* enc = (const float*)d_in[1];   // (32, 1024, 3072)
  const float* W1  = (const float*)d_in[2];   // (1024, 4096)
  const float* b1  = (const float*)d_in[3];   // (1024)
  const float* w2  = (const float*)d_in[4];   // (1, 1024)
  const float* W3  = (const float*)d_in[5];   // (1024, 3072)
  const float* b3  = (const float*)d_in[6];   // (1024)
  float* out = (float*)d_out;

  char* ws = (char*)d_ws;                     // ~14.7 MB used, all write-before-read
  unsigned short* W1a = (unsigned short*)(ws);          // 6,291,456 B
  float* pe    = (float*)(ws + 6291456);                // 32768*16*4 = 2,097,152 B
  float* alpha = (float*)(ws + 8388608);                // 131,072 B
  float* hb    = (float*)(ws + 8519680);                // 131,072 B
  float* ctx   = (float*)(ws + 8650752);                // 393,216 B
  float* part  = (float*)(ws + 9043968);                // 6,291,456 B

  convw1_kernel<<<3072, 256, 0, stream>>>(W1, W1a);
  hbias_kernel<<<8192, 256, 0, stream>>>(hs, W1, b1, hb);
  gemm_score<<<2048, 256, 0, stream>>>(enc, W1a, hb, w2, pe);
  softmax_kernel<<<32, 256, 0, stream>>>(pe, alpha);
  ctxpart_kernel<<<512, 256, 0, stream>>>(enc, alpha, part);
  ctxreduce_kernel<<<96, 256, 0, stream>>>(part, ctx);
  final_kernel<<<8192, 256, 0, stream>>>(ctx, W3, b3, out);
}